// Round 4
// baseline (577.447 us; speedup 1.0000x reference)
//
#include <hip/hip_runtime.h>
#include <hip/hip_bf16.h>
#include <stdint.h>

#define B_SZ 4096
#define F_SZ 3072
#define NCLS 1000
#define NE 8
#define NPAD 1024
#define CAP 4096
#define KSPLIT 2
#define KCH (F_SZ / KSPLIT)   // 1536

// workspace layout (bytes)
#define OFF_CNT   0          // 8 ints
#define OFF_LIST  1024       // 8*4096 ints = 131072
#define OFF_PAIR  132096     // 4096 ints
#define OFF_XB    262144     // 4096*3072 bf16 = 25165824
#define OFF_WT    25427968   // 8*1024*3072 bf16 = 50331648  (end ~75.8MB)

typedef unsigned short u16;
typedef __attribute__((ext_vector_type(8))) short short8v;  // 8 bf16 (4 VGPRs)
typedef __attribute__((ext_vector_type(4))) float f32x4;

__device__ __forceinline__ u16 f2bf(float f) {
  unsigned int u = __float_as_uint(f);
  u = (u + 0x7FFFu + ((u >> 16) & 1u)) >> 16;  // RNE, inputs are finite
  return (u16)u;
}

__device__ __forceinline__ void gll16(const void* g, void* l) {
  __builtin_amdgcn_global_load_lds(
      (const __attribute__((address_space(1))) void*)g,
      (__attribute__((address_space(3))) void*)l, 16, 0, 0);
}

// ---------------- ens_w f32 [e][k][n] -> bf16 wt [e][n][k] ----------------
__global__ __launch_bounds__(256) void transpose_w(const float* __restrict__ ensw,
                                                   u16* __restrict__ wt) {
  __shared__ u16 tile[64 * 264];   // [n][k], k-stride 264 (528B, b128-aligned)
  int t = threadIdx.x;
  int n0 = blockIdx.x * 64, k0 = blockIdx.y * 256, e = blockIdx.z;
  const float* src = ensw + (size_t)e * (F_SZ * NCLS);
  int kr = t >> 4, nq = (t & 15) * 4;
  for (int it = 0; it < 16; ++it) {
    int kk = it * 16 + kr;
    const float* sp = src + (size_t)(k0 + kk) * NCLS + n0 + nq;
    int n = n0 + nq;
    float4 v = make_float4(0.f, 0.f, 0.f, 0.f);
    if (n + 3 < NCLS) v = *(const float4*)sp;
    else {
      if (n     < NCLS) v.x = sp[0];
      if (n + 1 < NCLS) v.y = sp[1];
      if (n + 2 < NCLS) v.z = sp[2];
      if (n + 3 < NCLS) v.w = sp[3];
    }
    u16* d = tile + nq * 264 + kk;
    d[0]   = f2bf(v.x);
    d[264] = f2bf(v.y);
    d[528] = f2bf(v.z);
    d[792] = f2bf(v.w);
  }
  __syncthreads();
  int kc = t & 31, nr = t >> 5;
  for (int it = 0; it < 8; ++it) {
    int n = it * 8 + nr;
    uint4 pk = *(const uint4*)(tile + n * 264 + kc * 8);
    *(uint4*)(wt + ((size_t)(e * NPAD + n0 + n)) * F_SZ + k0 + kc * 8) = pk;
  }
}

// ---------------- selector CNN + routing + x->bf16 ----------------
#define XST 36
#define XCH 1152  // 32*36
__global__ __launch_bounds__(128) void selector(
    const float* __restrict__ x,
    const float* __restrict__ w1, const float* __restrict__ b1,
    const float* __restrict__ w2, const float* __restrict__ b2,
    const float* __restrict__ w3, const float* __restrict__ b3,
    const float* __restrict__ fw, const float* __restrict__ fb,
    u16* __restrict__ xb16, int* __restrict__ cnt, int* __restrict__ list,
    int* __restrict__ expair) {
  __shared__ float wgt[384];
  __shared__ float S[2][4704];
  int t = threadIdx.x;
  for (int i = t; i < 372; i += 128) {
    float v;
    if      (i <  75) v = w1[i];
    else if (i <  76) v = b1[i - 75];
    else if (i < 126) v = w2[i - 76];
    else if (i < 128) v = b2[i - 126];
    else if (i < 328) v = w3[i - 128];
    else if (i < 332) v = b3[i - 328];
    else if (i < 364) v = fw[i - 332];
    else              v = fb[i - 364];
    wgt[i] = v;
  }
  int w = t >> 6, l = t & 63;
  int b = blockIdx.x * 2 + w;
  float* xs   = S[w];
  float* buf1 = xs + 3456;  // 28x28
  float* p1   = xs + 4240;  // 14x14
  float* buf2 = xs + 4436;  // 2x10x10
  float* p2   = xs + 4636;  // 2x5x5
  float* hb   = xs + 4686;  // 4
  float* zb   = xs + 4690;  // 8

  const float4* gx = (const float4*)(x + (size_t)b * F_SZ);
  ushort4* gxb = (ushort4*)(xb16 + (size_t)b * F_SZ);
  for (int it = 0; it < 12; ++it) {
    int idx = it * 64 + l;
    float4 v = gx[idx];
    int f = idx * 4;
    int c = f >> 10, rem = f & 1023, y = rem >> 5, xc = rem & 31;
    *(float4*)(xs + c * XCH + y * XST + xc) = v;
    ushort4 h4;
    h4.x = f2bf(v.x); h4.y = f2bf(v.y); h4.z = f2bf(v.z); h4.w = f2bf(v.w);
    gxb[idx] = h4;
  }
  __syncthreads();

  if (l < 56) {
    int y = l >> 1, xh = l & 1;
    float acc[14];
#pragma unroll
    for (int xc = 0; xc < 14; ++xc) acc[xc] = wgt[75];
    for (int c = 0; c < 3; ++c)
      for (int i = 0; i < 5; ++i) {
        const float4* rb = (const float4*)(xs + c * XCH + (y + i) * XST) + xh * 3;
        float a[20];
#pragma unroll
        for (int q = 0; q < 5; ++q) {
          float4 v = rb[q];
          a[q * 4] = v.x; a[q * 4 + 1] = v.y; a[q * 4 + 2] = v.z; a[q * 4 + 3] = v.w;
        }
        if (xh) {
#pragma unroll
          for (int q = 0; q < 18; ++q) a[q] = a[q + 2];
        }
        const float* wp = wgt + c * 25 + i * 5;
        float W0 = wp[0], W1 = wp[1], W2 = wp[2], W3 = wp[3], W4 = wp[4];
#pragma unroll
        for (int xc = 0; xc < 14; ++xc)
          acc[xc] += a[xc] * W0 + a[xc + 1] * W1 + a[xc + 2] * W2 + a[xc + 3] * W3 + a[xc + 4] * W4;
      }
#pragma unroll
    for (int xc = 0; xc < 14; ++xc) buf1[y * 28 + xh * 14 + xc] = fmaxf(acc[xc], 0.f);
  }
  __syncthreads();

  for (int it = 0; it < 4; ++it) {
    int p = it * 64 + l;
    if (p < 196) {
      int py = p / 14, px = p % 14;
      const float* r0 = buf1 + (2 * py) * 28 + 2 * px;
      p1[p] = fmaxf(fmaxf(r0[0], r0[1]), fmaxf(r0[28], r0[29]));
    }
  }
  __syncthreads();

  for (int it = 0; it < 4; ++it) {
    int p = it * 64 + l;
    if (p < 200) {
      int o = p / 100, rem = p % 100, yy = rem / 10, xx = rem % 10;
      float acc = wgt[126 + o];
      const float* wp = wgt + 76 + o * 25;
#pragma unroll
      for (int i = 0; i < 5; ++i)
#pragma unroll
        for (int j = 0; j < 5; ++j) acc += p1[(yy + i) * 14 + xx + j] * wp[i * 5 + j];
      buf2[p] = fmaxf(acc, 0.f);
    }
  }
  __syncthreads();

  if (l < 50) {
    int o = l / 25, rem = l % 25, yy = rem / 5, xx = rem % 5;
    const float* r0 = buf2 + o * 100 + (2 * yy) * 10 + 2 * xx;
    p2[l] = fmaxf(fmaxf(r0[0], r0[1]), fmaxf(r0[10], r0[11]));
  }
  __syncthreads();

  if (l < 4) {
    float acc = wgt[328 + l];
    const float* wp = wgt + 128 + l * 50;
#pragma unroll
    for (int cc = 0; cc < 50; ++cc) acc += p2[cc] * wp[cc];
    hb[l] = fmaxf(acc, 0.f);
  }
  __syncthreads();

  if (l < 8) {
    float acc = wgt[364 + l];
    const float* wp = wgt + 332 + l * 4;
#pragma unroll
    for (int j = 0; j < 4; ++j) acc += hb[j] * wp[j];
    zb[l] = acc;
  }
  __syncthreads();

  if (l == 0) {
    float zz[8];
#pragma unroll
    for (int e = 0; e < 8; ++e) zz[e] = zb[e];
    int e1 = 0; float v1 = zz[0];
    for (int e = 1; e < 8; ++e) if (zz[e] > v1) { v1 = zz[e]; e1 = e; }
    int e2 = -1; float v2 = 0.f;
    for (int e = 0; e < 8; ++e) {
      if (e == e1) continue;
      if (e2 < 0 || zz[e] > v2) { v2 = zz[e]; e2 = e; }
    }
    int p1i = atomicAdd(&cnt[e1], 1); list[e1 * CAP + p1i] = b;
    int p2i = atomicAdd(&cnt[e2], 1); list[e2 * CAP + p2i] = b;
    expair[b] = e1 | (e2 << 8);
  }
}

// ---------------- out[b] = ens_b[e1] + ens_b[e2] ----------------
__global__ __launch_bounds__(256) void bias_init(const int* __restrict__ expair,
                                                 const float* __restrict__ ensb,
                                                 float* __restrict__ out) {
  int b = blockIdx.x;
  int t = threadIdx.x;
  if (t >= 250) return;
  int pr = expair[b];
  const float4* p1 = (const float4*)(ensb + (size_t)(pr & 255) * NCLS);
  const float4* p2 = (const float4*)(ensb + (size_t)((pr >> 8) & 255) * NCLS);
  float4* op = (float4*)(out + (size_t)b * NCLS);
  float4 a = p1[t], c = p2[t];
  float4 r; r.x = a.x + c.x; r.y = a.y + c.y; r.z = a.z + c.z; r.w = a.w + c.w;
  op[t] = r;
}

// ---------------- grouped gather-GEMM, 128x128, BK=32 dbuf, 1 barrier/step --
// 1D grid, XCD-swizzled: id%8 = (2e+ks)&7 pins each (expert, K-half) to one
// XCD; within a group n varies fastest (A-tile L2-hot), m outer (B-half
// 1.5MB + A-tile < 4MB L2 -> B re-reads hit L2). Double-buffered LDS (32.5KB
// -> 4 blocks/CU): stage s+1 issues before compute of s; one vmcnt-drain
// barrier per step so load latency hides under ds_read+MFMA.
__global__ __launch_bounds__(256, 4) void moe_gemm(const u16* __restrict__ xb,
                                                   const u16* __restrict__ wt,
                                                   const int* __restrict__ cnt,
                                                   const int* __restrict__ list,
                                                   float* __restrict__ out) {
  __shared__ u16 As[2][4096];   // [buf][128 rows][32 k], 16B-chunk XOR-4 swizzle
  __shared__ u16 Bs[2][4096];
  __shared__ int idx_s[128];
  int id = blockIdx.x;
  int gq = id & 15, q = id >> 4;
  int e  = gq >> 1, ks = gq & 1;
  int cnt_e = cnt[e];
  int m0 = (q >> 3) * 128;
  if (m0 >= cnt_e) return;
  int n0 = (q & 7) * 128;
  int t = threadIdx.x;
  const int* lst = list + e * CAP;
  if (t < 128) idx_s[t] = lst[min(m0 + t, cnt_e - 1)];  // clamp pad rows
  __syncthreads();

  // staging: 512 chunks/operand/step; instr j writes lds chunks j*256+t
  // (HW: wave-uniform base + lane*16). chunk c = row*4 + slot; stored global
  // k-chunk at slot is slot^(row&3), realized by pre-swizzling the SOURCE.
  int r0 = t >> 2, sl = t & 3;
  int gch = sl ^ (r0 & 3);            // same for r0 and r0+64 (64%4==0)
  size_t kbase = (size_t)ks * KCH + gch * 8;
  const u16* pA0 = xb + (size_t)idx_s[r0]      * F_SZ + kbase;
  const u16* pA1 = xb + (size_t)idx_s[r0 + 64] * F_SZ + kbase;
  const u16* pB0 = wt + ((size_t)(e * NPAD + n0 + r0))      * F_SZ + kbase;
  const u16* pB1 = wt + ((size_t)(e * NPAD + n0 + r0 + 64)) * F_SZ + kbase;
  int d0 = t * 8, d1 = (256 + t) * 8;  // u16 indices (byte = *2)

  int w = t >> 6, l = t & 63;
  int lr = l & 15, hk = l >> 4;
  int wrow = (w >> 1) * 64, wcol = (w & 1) * 64;
  int swz = (hk ^ (lr & 3)) * 8;      // read swizzle (row&3 == lr&3 here)
  int rA[4], rB[4];
#pragma unroll
  for (int i = 0; i < 4; ++i) {
    rA[i] = (wrow + i * 16 + lr) * 32 + swz;
    rB[i] = (wcol + i * 16 + lr) * 32 + swz;
  }

  // prologue: stage step 0 into buf 0
  gll16(pA0, &As[0][d0]); gll16(pA1, &As[0][d1]);
  gll16(pB0, &Bs[0][d0]); gll16(pB1, &Bs[0][d1]);
  pA0 += 32; pA1 += 32; pB0 += 32; pB1 += 32;
  __syncthreads();

  f32x4 acc[4][4] = {};
  const int NS = KCH / 32;  // 48
  for (int s = 0; s < NS; ++s) {
    int cur = s & 1;
    if (s + 1 < NS) {
      int nxt = cur ^ 1;
      gll16(pA0, &As[nxt][d0]); gll16(pA1, &As[nxt][d1]);
      gll16(pB0, &Bs[nxt][d0]); gll16(pB1, &Bs[nxt][d1]);
      pA0 += 32; pA1 += 32; pB0 += 32; pB1 += 32;
    }
    short8v av[4], bv[4];
#pragma unroll
    for (int i = 0; i < 4; ++i) av[i] = *(const short8v*)(&As[cur][rA[i]]);
#pragma unroll
    for (int j = 0; j < 4; ++j) bv[j] = *(const short8v*)(&Bs[cur][rB[j]]);
#pragma unroll
    for (int i = 0; i < 4; ++i)
#pragma unroll
      for (int j = 0; j < 4; ++j)
        acc[i][j] = __builtin_amdgcn_mfma_f32_16x16x32_bf16(av[i], bv[j], acc[i][j], 0, 0, 0);
    __syncthreads();  // drains vmcnt(0): nxt-stage latency was covered by MFMA
  }

  // epilogue: scatter-add (each sample hit by exactly 2 experts x KSPLIT)
#pragma unroll
  for (int i = 0; i < 4; ++i) {
#pragma unroll
    for (int r = 0; r < 4; ++r) {
      int mt = wrow + i * 16 + hk * 4 + r;
      if (m0 + mt < cnt_e) {
        float* orow = out + (size_t)idx_s[mt] * NCLS;
#pragma unroll
        for (int j = 0; j < 4; ++j) {
          int col = n0 + wcol + j * 16 + lr;
          if (col < NCLS) unsafeAtomicAdd(orow + col, acc[i][j][r]);
        }
      }
    }
  }
}

extern "C" void kernel_launch(void* const* d_in, const int* in_sizes, int n_in,
                              void* d_out, int out_size, void* d_ws, size_t ws_size,
                              hipStream_t stream) {
  const float* x   = (const float*)d_in[0];
  const float* w1  = (const float*)d_in[1];
  const float* b1  = (const float*)d_in[2];
  const float* w2  = (const float*)d_in[3];
  const float* b2  = (const float*)d_in[4];
  const float* w3  = (const float*)d_in[5];
  const float* b3  = (const float*)d_in[6];
  const float* fw  = (const float*)d_in[7];
  const float* fb  = (const float*)d_in[8];
  const float* ensw = (const float*)d_in[9];
  const float* ensb = (const float*)d_in[10];
  float* out = (float*)d_out;

  uint8_t* ws = (uint8_t*)d_ws;
  int* cnt    = (int*)(ws + OFF_CNT);
  int* list   = (int*)(ws + OFF_LIST);
  int* expair = (int*)(ws + OFF_PAIR);
  u16* xb16   = (u16*)(ws + OFF_XB);
  u16* wt     = (u16*)(ws + OFF_WT);

  hipMemsetAsync(cnt, 0, 64, stream);
  transpose_w<<<dim3(16, 12, 8), 256, 0, stream>>>(ensw, wt);
  selector<<<2048, 128, 0, stream>>>(x, w1, b1, w2, b2, w3, b3, fw, fb,
                                     xb16, cnt, list, expair);
  bias_init<<<4096, 256, 0, stream>>>(expair, ensb, out);
  moe_gemm<<<4096, 256, 0, stream>>>(xb16, wt, cnt, list, out);
}

// Round 6
// 576.413 us; speedup vs baseline: 1.0018x; 1.0018x over previous
//
#include <hip/hip_runtime.h>
#include <hip/hip_bf16.h>
#include <stdint.h>

#define B_SZ 4096
#define F_SZ 3072
#define NCLS 1000
#define NE 8
#define NPAD 1024
#define CAP 4096
#define KSPLIT 2
#define KCH (F_SZ / KSPLIT)   // 1536

// workspace layout (bytes)
#define OFF_CNT   0          // 8 ints
#define OFF_LIST  1024       // 8*4096 ints = 131072
#define OFF_XB    262144     // 4096*3072 bf16 = 25165824
#define OFF_WT    25427968   // 8*1024*3072 bf16 = 50331648  (end ~75.8MB)

typedef unsigned short u16;
typedef __attribute__((ext_vector_type(8))) short short8v;  // 8 bf16 (4 VGPRs)
typedef __attribute__((ext_vector_type(4))) float f32x4;

__device__ __forceinline__ u16 f2bf(float f) {
  unsigned int u = __float_as_uint(f);
  u = (u + 0x7FFFu + ((u >> 16) & 1u)) >> 16;  // RNE, inputs are finite
  return (u16)u;
}

__device__ __forceinline__ void gll16(const void* g, void* l) {
  __builtin_amdgcn_global_load_lds(
      (const __attribute__((address_space(1))) void*)g,
      (__attribute__((address_space(3))) void*)l, 16, 0, 0);
}

// ---------------- ens_w f32 [e][k][n] -> bf16 wt [e][n][k] ----------------
__global__ __launch_bounds__(256) void transpose_w(const float* __restrict__ ensw,
                                                   u16* __restrict__ wt) {
  __shared__ u16 tile[64 * 264];   // [n][k], k-stride 264 (528B, b128-aligned)
  int t = threadIdx.x;
  int n0 = blockIdx.x * 64, k0 = blockIdx.y * 256, e = blockIdx.z;
  const float* src = ensw + (size_t)e * (F_SZ * NCLS);
  int kr = t >> 4, nq = (t & 15) * 4;
  for (int it = 0; it < 16; ++it) {
    int kk = it * 16 + kr;
    const float* sp = src + (size_t)(k0 + kk) * NCLS + n0 + nq;
    int n = n0 + nq;
    float4 v = make_float4(0.f, 0.f, 0.f, 0.f);
    if (n + 3 < NCLS) v = *(const float4*)sp;
    else {
      if (n     < NCLS) v.x = sp[0];
      if (n + 1 < NCLS) v.y = sp[1];
      if (n + 2 < NCLS) v.z = sp[2];
      if (n + 3 < NCLS) v.w = sp[3];
    }
    u16* d = tile + nq * 264 + kk;
    d[0]   = f2bf(v.x);
    d[264] = f2bf(v.y);
    d[528] = f2bf(v.z);
    d[792] = f2bf(v.w);
  }
  __syncthreads();
  int kc = t & 31, nr = t >> 5;
  for (int it = 0; it < 8; ++it) {
    int n = it * 8 + nr;
    uint4 pk = *(const uint4*)(tile + n * 264 + kc * 8);
    *(uint4*)(wt + ((size_t)(e * NPAD + n0 + n)) * F_SZ + k0 + kc * 8) = pk;
  }
}

// ---------------- selector CNN + routing + x->bf16 + bias write ----------
#define XST 36
#define XCH 1152  // 32*36
__global__ __launch_bounds__(128) void selector(
    const float* __restrict__ x,
    const float* __restrict__ w1, const float* __restrict__ b1,
    const float* __restrict__ w2, const float* __restrict__ b2,
    const float* __restrict__ w3, const float* __restrict__ b3,
    const float* __restrict__ fw, const float* __restrict__ fb,
    const float* __restrict__ ensb,
    u16* __restrict__ xb16, int* __restrict__ cnt, int* __restrict__ list,
    float* __restrict__ out) {
  __shared__ float wgt[384];
  __shared__ float S[2][4704];
  int t = threadIdx.x;
  for (int i = t; i < 372; i += 128) {
    float v;
    if      (i <  75) v = w1[i];
    else if (i <  76) v = b1[i - 75];
    else if (i < 126) v = w2[i - 76];
    else if (i < 128) v = b2[i - 126];
    else if (i < 328) v = w3[i - 128];
    else if (i < 332) v = b3[i - 328];
    else if (i < 364) v = fw[i - 332];
    else              v = fb[i - 364];
    wgt[i] = v;
  }
  int w = t >> 6, l = t & 63;
  int b = blockIdx.x * 2 + w;
  float* xs   = S[w];
  float* buf1 = xs + 3456;  // 28x28
  float* p1   = xs + 4240;  // 14x14
  float* buf2 = xs + 4436;  // 2x10x10
  float* p2   = xs + 4636;  // 2x5x5
  float* hb   = xs + 4686;  // 4
  float* zb   = xs + 4690;  // 8

  const float4* gx = (const float4*)(x + (size_t)b * F_SZ);
  ushort4* gxb = (ushort4*)(xb16 + (size_t)b * F_SZ);
  for (int it = 0; it < 12; ++it) {
    int idx = it * 64 + l;
    float4 v = gx[idx];
    int f = idx * 4;
    int c = f >> 10, rem = f & 1023, y = rem >> 5, xc = rem & 31;
    *(float4*)(xs + c * XCH + y * XST + xc) = v;
    ushort4 h4;
    h4.x = f2bf(v.x); h4.y = f2bf(v.y); h4.z = f2bf(v.z); h4.w = f2bf(v.w);
    gxb[idx] = h4;
  }
  __syncthreads();

  if (l < 56) {
    int y = l >> 1, xh = l & 1;
    float acc[14];
#pragma unroll
    for (int xc = 0; xc < 14; ++xc) acc[xc] = wgt[75];
    for (int c = 0; c < 3; ++c)
      for (int i = 0; i < 5; ++i) {
        const float4* rb = (const float4*)(xs + c * XCH + (y + i) * XST) + xh * 3;
        float a[20];
#pragma unroll
        for (int q = 0; q < 5; ++q) {
          float4 v = rb[q];
          a[q * 4] = v.x; a[q * 4 + 1] = v.y; a[q * 4 + 2] = v.z; a[q * 4 + 3] = v.w;
        }
        if (xh) {
#pragma unroll
          for (int q = 0; q < 18; ++q) a[q] = a[q + 2];
        }
        const float* wp = wgt + c * 25 + i * 5;
        float W0 = wp[0], W1 = wp[1], W2 = wp[2], W3 = wp[3], W4 = wp[4];
#pragma unroll
        for (int xc = 0; xc < 14; ++xc)
          acc[xc] += a[xc] * W0 + a[xc + 1] * W1 + a[xc + 2] * W2 + a[xc + 3] * W3 + a[xc + 4] * W4;
      }
#pragma unroll
    for (int xc = 0; xc < 14; ++xc) buf1[y * 28 + xh * 14 + xc] = fmaxf(acc[xc], 0.f);
  }
  __syncthreads();

  for (int it = 0; it < 4; ++it) {
    int p = it * 64 + l;
    if (p < 196) {
      int py = p / 14, px = p % 14;
      const float* r0 = buf1 + (2 * py) * 28 + 2 * px;
      p1[p] = fmaxf(fmaxf(r0[0], r0[1]), fmaxf(r0[28], r0[29]));
    }
  }
  __syncthreads();

  for (int it = 0; it < 4; ++it) {
    int p = it * 64 + l;
    if (p < 200) {
      int o = p / 100, rem = p % 100, yy = rem / 10, xx = rem % 10;
      float acc = wgt[126 + o];
      const float* wp = wgt + 76 + o * 25;
#pragma unroll
      for (int i = 0; i < 5; ++i)
#pragma unroll
        for (int j = 0; j < 5; ++j) acc += p1[(yy + i) * 14 + xx + j] * wp[i * 5 + j];
      buf2[p] = fmaxf(acc, 0.f);
    }
  }
  __syncthreads();

  if (l < 50) {
    int o = l / 25, rem = l % 25, yy = rem / 5, xx = rem % 5;
    const float* r0 = buf2 + o * 100 + (2 * yy) * 10 + 2 * xx;
    p2[l] = fmaxf(fmaxf(r0[0], r0[1]), fmaxf(r0[10], r0[11]));
  }
  __syncthreads();

  if (l < 4) {
    float acc = wgt[328 + l];
    const float* wp = wgt + 128 + l * 50;
#pragma unroll
    for (int cc = 0; cc < 50; ++cc) acc += p2[cc] * wp[cc];
    hb[l] = fmaxf(acc, 0.f);
  }
  __syncthreads();

  if (l < 8) {
    float acc = wgt[364 + l];
    const float* wp = wgt + 332 + l * 4;
#pragma unroll
    for (int j = 0; j < 4; ++j) acc += hb[j] * wp[j];
    zb[l] = acc;
  }
  __syncthreads();

  // top-2 (L2-norm is a positive scale: order-preserving -> skip)
  int pr = 0;
  if (l == 0) {
    float zz[8];
#pragma unroll
    for (int e = 0; e < 8; ++e) zz[e] = zb[e];
    int e1 = 0; float v1 = zz[0];
    for (int e = 1; e < 8; ++e) if (zz[e] > v1) { v1 = zz[e]; e1 = e; }
    int e2 = -1; float v2 = 0.f;
    for (int e = 0; e < 8; ++e) {
      if (e == e1) continue;
      if (e2 < 0 || zz[e] > v2) { v2 = zz[e]; e2 = e; }
    }
    int p1i = atomicAdd(&cnt[e1], 1); list[e1 * CAP + p1i] = b;
    int p2i = atomicAdd(&cnt[e2], 1); list[e2 * CAP + p2i] = b;
    pr = e1 | (e2 << 8);
  }
  // broadcast expert pair to the wave; write out[b] = ens_b[e1] + ens_b[e2]
  pr = __shfl(pr, 0);
  const float4* q1 = (const float4*)(ensb + (size_t)(pr & 255) * NCLS);
  const float4* q2 = (const float4*)(ensb + (size_t)((pr >> 8) & 255) * NCLS);
  float4* op = (float4*)(out + (size_t)b * NCLS);
#pragma unroll
  for (int it = 0; it < 4; ++it) {
    int idx = it * 64 + l;
    if (idx < 250) {
      float4 a = q1[idx], c = q2[idx];
      float4 r; r.x = a.x + c.x; r.y = a.y + c.y; r.z = a.z + c.z; r.w = a.w + c.w;
      op[idx] = r;
    }
  }
}

// ---------------- grouped gather-GEMM, 128x128, BK=32 dbuf ----------------
// Counted-vmcnt pipeline (T3+T4 minimum form): raw s_barrier + asm
// s_waitcnt vmcnt(4) (never 0 in-loop); stage buf[cur] for step s+2 after
// the readers' barrier. Swizzle: lds slot' = slot ^ ((row>>1)&3) (row stride
// 64B = 16 dwords -> rows alternate bank halves; (row>>1) pairs complement).
// XCD-pinned 1D grid: id%8 = (2e+ks)&7 (r4: FETCH 194->72MB).
__global__ __launch_bounds__(256, 4) void moe_gemm(const u16* __restrict__ xb,
                                                   const u16* __restrict__ wt,
                                                   const int* __restrict__ cnt,
                                                   const int* __restrict__ list,
                                                   float* __restrict__ out) {
  __shared__ u16 As[2][4096];   // [buf][128 rows][32 k]
  __shared__ u16 Bs[2][4096];
  __shared__ int idx_s[128];
  int id = blockIdx.x;
  int gq = id & 15, q = id >> 4;
  int e  = gq >> 1, ks = gq & 1;
  int cnt_e = cnt[e];
  int m0 = (q >> 3) * 128;
  if (m0 >= cnt_e) return;
  int n0 = (q & 7) * 128;
  int t = threadIdx.x;
  const int* lst = list + e * CAP;
  if (t < 128) idx_s[t] = lst[min(m0 + t, cnt_e - 1)];  // clamp pad rows
  __syncthreads();

  // staging: 512 chunks/operand/step; chunk c = q*256+t: row=c>>2, slot=c&3.
  // source chunk g = slot ^ ((row>>1)&3)  (thread-constant: 64>>1 % 4 == 0)
  int g = (t & 3) ^ ((t >> 3) & 3);
  size_t kbase = (size_t)ks * KCH + g * 8;
  int r0 = t >> 2;
  const u16* pA0 = xb + (size_t)idx_s[r0]      * F_SZ + kbase;
  const u16* pA1 = xb + (size_t)idx_s[r0 + 64] * F_SZ + kbase;
  const u16* pB0 = wt + ((size_t)(e * NPAD + n0 + r0))      * F_SZ + kbase;
  const u16* pB1 = wt + ((size_t)(e * NPAD + n0 + r0 + 64)) * F_SZ + kbase;
  int d0 = t * 8, d1 = (256 + t) * 8;  // u16 indices

  int w = t >> 6, l = t & 63;
  int lr = l & 15, hk = l >> 4;
  int wrow = (w >> 1) * 64, wcol = (w & 1) * 64;
  int slot = (hk ^ ((lr >> 1) & 3)) * 8;
  int rA[4], rB[4];
#pragma unroll
  for (int i = 0; i < 4; ++i) {
    rA[i] = (wrow + i * 16 + lr) * 32 + slot;
    rB[i] = (wcol + i * 16 + lr) * 32 + slot;
  }

#define STAGE(BUF)                                              \
  { gll16(pA0, &As[BUF][d0]); gll16(pA1, &As[BUF][d1]);         \
    gll16(pB0, &Bs[BUF][d0]); gll16(pB1, &Bs[BUF][d1]);         \
    pA0 += 32; pA1 += 32; pB0 += 32; pB1 += 32; }

  // prologue: two K-steps in flight (8 outstanding loads)
  STAGE(0);
  STAGE(1);

  f32x4 acc[4][4] = {};
  const int NS = KCH / 32;  // 48
  for (int s = 0; s < NS - 1; ++s) {
    int cur = s & 1;
    asm volatile("s_waitcnt vmcnt(4)" ::: "memory");  // buf[cur] landed; next stays in flight
    __builtin_amdgcn_s_barrier();
    asm volatile("" ::: "memory");
    short8v av[4], bv[4];
#pragma unroll
    for (int i = 0; i < 4; ++i) av[i] = *(const short8v*)(&As[cur][rA[i]]);
#pragma unroll
    for (int j = 0; j < 4; ++j) bv[j] = *(const short8v*)(&Bs[cur][rB[j]]);
    __builtin_amdgcn_s_setprio(1);
#pragma unroll
    for (int i = 0; i < 4; ++i)
#pragma unroll
      for (int j = 0; j < 4; ++j)
        acc[i][j] = __builtin_amdgcn_mfma_f32_16x16x32_bf16(av[i], bv[j], acc[i][j], 0, 0, 0);
    __builtin_amdgcn_s_setprio(0);
    asm volatile("" ::: "memory");
    __builtin_amdgcn_s_barrier();   // readers of buf[cur] done -> safe to restage
    if (s + 2 < NS) STAGE(cur)
  }
  {  // peeled last step: drain fully
    int cur = (NS - 1) & 1;
    asm volatile("s_waitcnt vmcnt(0)" ::: "memory");
    __builtin_amdgcn_s_barrier();
    asm volatile("" ::: "memory");
    short8v av[4], bv[4];
#pragma unroll
    for (int i = 0; i < 4; ++i) av[i] = *(const short8v*)(&As[cur][rA[i]]);
#pragma unroll
    for (int j = 0; j < 4; ++j) bv[j] = *(const short8v*)(&Bs[cur][rB[j]]);
    __builtin_amdgcn_s_setprio(1);
#pragma unroll
    for (int i = 0; i < 4; ++i)
#pragma unroll
      for (int j = 0; j < 4; ++j)
        acc[i][j] = __builtin_amdgcn_mfma_f32_16x16x32_bf16(av[i], bv[j], acc[i][j], 0, 0, 0);
    __builtin_amdgcn_s_setprio(0);
  }
#undef STAGE

  // epilogue: scatter-add (each sample hit by exactly 2 experts x KSPLIT)
#pragma unroll
  for (int i = 0; i < 4; ++i) {
#pragma unroll
    for (int r = 0; r < 4; ++r) {
      int mt = wrow + i * 16 + hk * 4 + r;
      if (m0 + mt < cnt_e) {
        float* orow = out + (size_t)idx_s[mt] * NCLS;
#pragma unroll
        for (int j = 0; j < 4; ++j) {
          int col = n0 + wcol + j * 16 + lr;
          if (col < NCLS) unsafeAtomicAdd(orow + col, acc[i][j][r]);
        }
      }
    }
  }
}

extern "C" void kernel_launch(void* const* d_in, const int* in_sizes, int n_in,
                              void* d_out, int out_size, void* d_ws, size_t ws_size,
                              hipStream_t stream) {
  const float* x   = (const float*)d_in[0];
  const float* w1  = (const float*)d_in[1];
  const float* b1  = (const float*)d_in[2];
  const float* w2  = (const float*)d_in[3];
  const float* b2  = (const float*)d_in[4];
  const float* w3  = (const float*)d_in[5];
  const float* b3  = (const float*)d_in[6];
  const float* fw  = (const float*)d_in[7];
  const float* fb  = (const float*)d_in[8];
  const float* ensw = (const float*)d_in[9];
  const float* ensb = (const float*)d_in[10];
  float* out = (float*)d_out;

  uint8_t* ws = (uint8_t*)d_ws;
  int* cnt    = (int*)(ws + OFF_CNT);
  int* list   = (int*)(ws + OFF_LIST);
  u16* xb16   = (u16*)(ws + OFF_XB);
  u16* wt     = (u16*)(ws + OFF_WT);

  hipMemsetAsync(cnt, 0, 64, stream);
  transpose_w<<<dim3(16, 12, 8), 256, 0, stream>>>(ensw, wt);
  selector<<<2048, 128, 0, stream>>>(x, w1, b1, w2, b2, w3, b3, fw, fb, ensb,
                                     xb16, cnt, list, out);
  moe_gemm<<<4096, 256, 0, stream>>>(xb16, wt, cnt, list, out);
}